// Round 11
// baseline (798.946 us; speedup 1.0000x reference)
//
#include <hip/hip_runtime.h>
#include <hip/hip_bf16.h>

// Problem constants (match reference)
#define B_DIM 8192
#define D_DIM 1024
#define N_DIM 4096
#define TAU_INV 5.0f

typedef __bf16 bf16x8 __attribute__((ext_vector_type(8)));
typedef __bf16 bf16x4 __attribute__((ext_vector_type(4)));
typedef float  f32x4  __attribute__((ext_vector_type(4)));

// ---------------------------------------------------------------------------
__device__ __forceinline__ void gld_lds16(const void* g, void* l) {
  __builtin_amdgcn_global_load_lds((const __attribute__((address_space(1))) void*)g,
                                   (__attribute__((address_space(3))) void*)l,
                                   16, 0, 0);
}
__device__ __forceinline__ float fast_rcp(float x) {
  return __builtin_amdgcn_rcpf(x);
}
#define MFMA(a, b, c) __builtin_amdgcn_mfma_f32_16x16x32_bf16((a), (b), (c), 0, 0, 0)

// ---------------------------------------------------------------------------
// prep_x: x (f32 [B,D]) -> xh (bf16). Single-term bf16 GEMM: measured absmax
// 0.015625 (= comparison floor) with 0.064 threshold — verified round 10.
__global__ void prep_x(const float* __restrict__ x, __bf16* __restrict__ xh) {
  const int i = blockIdx.x * blockDim.x + threadIdx.x;
  const int base = i * 4;
  const float4 v = *reinterpret_cast<const float4*>(x + base);
  bf16x4 h;
  h[0] = (__bf16)v.x; h[1] = (__bf16)v.y; h[2] = (__bf16)v.z; h[3] = (__bf16)v.w;
  *reinterpret_cast<bf16x4*>(xh + base) = h;
}

// ---------------------------------------------------------------------------
// prep_w: W (f32 [D,N]) -> wht (bf16 [N,D]) transposed
__global__ void prep_w(const float* __restrict__ W, __bf16* __restrict__ wht) {
  __shared__ float tile[32][33];
  const int tn = blockIdx.x & 127;
  const int tk = blockIdx.x >> 7;
  const int tx = threadIdx.x & 31;
  const int ty = threadIdx.x >> 5;
#pragma unroll
  for (int r = 0; r < 4; ++r) {
    const int k = tk * 32 + ty + r * 8;
    tile[ty + r * 8][tx] = W[(size_t)k * N_DIM + tn * 32 + tx];
  }
  __syncthreads();
#pragma unroll
  for (int r = 0; r < 4; ++r) {
    const int nn = tn * 32 + ty + r * 8;
    const int kk = tk * 32 + tx;
    wht[(size_t)nn * D_DIM + kk] = (__bf16)tile[tx][ty + r * 8];
  }
}

// ---------------------------------------------------------------------------
// Fused GEMM: 128x256 tile, BK=32, K=1024 single-term bf16, 8 waves (2Mx4N),
// wave tile 64x64 (acc 64 VGPR). TLP variant: SINGLE-buffered 24 KB tile
// (32 KB LDS block incl. Ebuf alias) + __launch_bounds__(512,8) -> 4
// blocks/CU (32 waves): per-block stage stalls hide under the other blocks'
// compute, and epilogue HBM bursts desync across blocks. Rotation swizzle
// (measured 0 conflicts), setprio, transposed epilogue.
#define BM 128
#define BN 256
#define BK 32
#define THREADS 512

__global__ __launch_bounds__(THREADS, 8) void gemm_fused(
    const __bf16* __restrict__ xh,
    const __bf16* __restrict__ wht,
    const float* __restrict__ bias, const float* __restrict__ gumbel,
    const int* __restrict__ flags, float* __restrict__ out) {
  __shared__ __align__(16) unsigned char smem[32768];
  __bf16* As = reinterpret_cast<__bf16*>(smem);          // 8 KB
  __bf16* Bs = reinterpret_cast<__bf16*>(smem + 8192);   // 16 KB
  float* Ebuf = reinterpret_cast<float*>(smem);          // 32 KB (epilogue)

  const int tid  = threadIdx.x;
  const int lane = tid & 63;
  const int wave = tid >> 6;
  const int wr   = wave >> 2;      // 0..1 (M, 64 rows each)
  const int wc   = wave & 3;       // 0..3 (N, 64 cols each)
  const int fr   = lane & 15;
  const int q4   = lane >> 4;
  // rotation swizzle (round-5, measured conflict-free): slot = (q4 + (fr>>1)) & 3
  const int prot8 = ((q4 + ((fr >> 1) & 3)) & 3) * 8;

  // XCD swizzle: 1024 blocks; each XCD owns 8 row-panels x 16 col-panels
  const int bx  = blockIdx.x;
  const int xcd = bx & 7;
  const int ii  = bx >> 3;         // 0..127
  const int tn  = ii >> 3;         // 0..15
  const int tm  = xcd * 8 + (ii & 7);  // 0..63
  const int row0 = tm * BM;
  const int col0 = tn * BN;

  // staging geometry: chunk c -> row c>>2, phys slot c&3,
  // logical (global) slot l = (p - (row>>1)) & 3 (inverse of read rotation)
  const int r0 = tid >> 2;                               // 0..127
  const int l8 = (((tid & 3) - ((tid >> 3) & 3)) & 3) * 8;

  const __bf16* Ahi = xh  + (size_t)row0 * D_DIM;
  const __bf16* Bsc = wht + (size_t)col0 * D_DIM;

#define STAGE(t_)                                                            \
  do {                                                                       \
    const int ko_ = (t_) * 32;                                               \
    gld_lds16(Ahi + (size_t)r0 * D_DIM + ko_ + l8, &As[tid * 8]);            \
    gld_lds16(Bsc + (size_t)r0 * D_DIM + ko_ + l8, &Bs[tid * 8]);            \
    gld_lds16(Bsc + (size_t)(128 + r0) * D_DIM + ko_ + l8,                   \
              &Bs[(512 + tid) * 8]);                                         \
  } while (0)

#define COMPUTE                                                              \
  {                                                                          \
    bf16x8 bfr_[4];                                                          \
    _Pragma("unroll")                                                        \
    for (int n = 0; n < 4; ++n)                                              \
      bfr_[n] = *reinterpret_cast<const bf16x8*>(                            \
          &Bs[(wc * 64 + n * 16 + fr) * BK + prot8]);                        \
    __builtin_amdgcn_s_setprio(1);                                           \
    _Pragma("unroll")                                                        \
    for (int m = 0; m < 4; ++m) {                                            \
      const bf16x8 av_ = *reinterpret_cast<const bf16x8*>(                   \
          &As[(wr * 64 + m * 16 + fr) * BK + prot8]);                        \
      _Pragma("unroll")                                                      \
      for (int n = 0; n < 4; ++n)                                            \
        acc[m][n] = MFMA(bfr_[n], av_, acc[m][n]);                           \
    }                                                                        \
    __builtin_amdgcn_s_setprio(0);                                           \
  }

#define VM0 asm volatile("s_waitcnt vmcnt(0)" ::: "memory")
#define BAR __builtin_amdgcn_s_barrier()

  f32x4 acc[4][4];
#pragma unroll
  for (int m = 0; m < 4; ++m)
#pragma unroll
    for (int n = 0; n < 4; ++n) acc[m][n] = (f32x4){0.f, 0.f, 0.f, 0.f};

#pragma unroll 1
  for (int t = 0; t < 32; ++t) {
    STAGE(t);
    VM0; BAR;
    COMPUTE
    BAR;
  }

  // ---- LDS-transposed epilogue ----
  // 4 chunks of 32 rows. Owner waves (wr == ck>>1) write acc frags into
  // Ebuf[32][256] floats (16B-slot XOR swizzle on low 3 bits), then all 8
  // waves stream back row-contiguous (wave w, round rr -> row rr*8+w,
  // lanes cover 256 cols) -> 1 KB contiguous wave-segments for out0/out1
  // stores and gumbel loads.
  float* out0 = out;
  float* out1 = out + (size_t)B_DIM * N_DIM;

  const int tcol = tid & 63;            // 16B col-chunk within 256-col tile
  const int gcol = col0 + tcol * 4;
  const float4 bias4 = *reinterpret_cast<const float4*>(bias + gcol);
  const int flag = flags[(col0 >> 4) + (tcol >> 2)];

#pragma unroll
  for (int ck = 0; ck < 4; ++ck) {
    __syncthreads();   // prior chunk reads / K-loop LDS use complete
    if (wr == (ck >> 1)) {
#pragma unroll
      for (int mi = 0; mi < 2; ++mi) {
        const int lrow = mi * 16 + fr;          // 0..31
        const int m = (ck & 1) * 2 + mi;
#pragma unroll
        for (int n = 0; n < 4; ++n) {
          const int s = (wc * 16 + n * 4 + q4) ^ (lrow & 7);  // 16B slot 0..63
          *reinterpret_cast<f32x4*>(&Ebuf[lrow * 256 + s * 4]) = acc[m][n];
        }
      }
    }
    __syncthreads();
#pragma unroll
    for (int rr = 0; rr < 4; ++rr) {
      const int lrow = rr * 8 + wave;           // 0..31
      const int grow = row0 + ck * 32 + lrow;
      const f32x4 a = *reinterpret_cast<const f32x4*>(
          &Ebuf[lrow * 256 + (tcol ^ (lrow & 7)) * 4]);
      const size_t idx = (size_t)grow * N_DIM + gcol;
      const float o0 = a[0] + bias4.x;
      const float o1 = a[1] + bias4.y;
      const float o2 = a[2] + bias4.z;
      const float o3 = a[3] + bias4.w;
      *reinterpret_cast<float4*>(out0 + idx) = make_float4(o0, o1, o2, o3);

      float4 v;
      if (flag == 0) {
        const float c0 = fminf(fmaxf(o0, -15.f), 15.f);
        const float c1 = fminf(fmaxf(o1, -15.f), 15.f);
        const float c2 = fminf(fmaxf(o2, -15.f), 15.f);
        const float c3 = fminf(fmaxf(o3, -15.f), 15.f);
        const float e0 = __expf(2.f * c0), e1 = __expf(2.f * c1);
        const float e2 = __expf(2.f * c2), e3 = __expf(2.f * c3);
        v.x = (e0 - 1.f) * fast_rcp(e0 + 1.f);
        v.y = (e1 - 1.f) * fast_rcp(e1 + 1.f);
        v.z = (e2 - 1.f) * fast_rcp(e2 + 1.f);
        v.w = (e3 - 1.f) * fast_rcp(e3 + 1.f);
      } else {
        // 16-wide segment = 4 adjacent lanes: shfl_xor 1,2
        const float4 g = *reinterpret_cast<const float4*>(gumbel + idx);
        const float t0 = (o0 + g.x) * TAU_INV;
        const float t1 = (o1 + g.y) * TAU_INV;
        const float t2 = (o2 + g.z) * TAU_INV;
        const float t3 = (o3 + g.w) * TAU_INV;
        float mx = fmaxf(fmaxf(t0, t1), fmaxf(t2, t3));
        mx = fmaxf(mx, __shfl_xor(mx, 1));
        mx = fmaxf(mx, __shfl_xor(mx, 2));
        const float e0 = __expf(t0 - mx), e1 = __expf(t1 - mx);
        const float e2 = __expf(t2 - mx), e3 = __expf(t3 - mx);
        float s = (e0 + e1) + (e2 + e3);
        s += __shfl_xor(s, 1);
        s += __shfl_xor(s, 2);
        const float inv = fast_rcp(s);
        v.x = e0 * inv; v.y = e1 * inv; v.z = e2 * inv; v.w = e3 * inv;
      }
      *reinterpret_cast<float4*>(out1 + idx) = v;
    }
  }
}

// ---------------------------------------------------------------------------
// fallback (only if ws_size too small): naive but correct
__global__ void fallback_kernel(const float* __restrict__ x, const float* __restrict__ W,
                                const float* __restrict__ bias, const float* __restrict__ gumbel,
                                const int* __restrict__ flags, float* __restrict__ out) {
  const size_t idx = (size_t)blockIdx.x * blockDim.x + threadIdx.x;
  const int row = (int)(idx / N_DIM);
  const int col = (int)(idx % N_DIM);
  float o = bias[col];
  const float* xr = x + (size_t)row * D_DIM;
  for (int k = 0; k < D_DIM; ++k) o += xr[k] * W[(size_t)k * N_DIM + col];
  out[idx] = o;
  float v;
  if (flags[col >> 4] == 0) {
    const float oc = fminf(fmaxf(o, -15.f), 15.f);
    const float e2 = __expf(2.f * oc);
    v = (e2 - 1.f) / (e2 + 1.f);
  } else {
    const float t = (o + gumbel[idx]) * TAU_INV;
    float mx = t;
    mx = fmaxf(mx, __shfl_xor(mx, 1));
    mx = fmaxf(mx, __shfl_xor(mx, 2));
    mx = fmaxf(mx, __shfl_xor(mx, 4));
    mx = fmaxf(mx, __shfl_xor(mx, 8));
    float e = __expf(t - mx);
    float ssum = e;
    ssum += __shfl_xor(ssum, 1);
    ssum += __shfl_xor(ssum, 2);
    ssum += __shfl_xor(ssum, 4);
    ssum += __shfl_xor(ssum, 8);
    v = e / ssum;
  }
  out[(size_t)B_DIM * N_DIM + idx] = v;
}

// ---------------------------------------------------------------------------
extern "C" void kernel_launch(void* const* d_in, const int* in_sizes, int n_in,
                              void* d_out, int out_size, void* d_ws, size_t ws_size,
                              hipStream_t stream) {
  const float* x      = (const float*)d_in[0];
  const float* W      = (const float*)d_in[1];
  const float* bias   = (const float*)d_in[2];
  const float* gumbel = (const float*)d_in[3];
  const int*   flags  = (const int*)d_in[4];
  float* out = (float*)d_out;

  const size_t xcnt = (size_t)B_DIM * D_DIM;
  const size_t wcnt = (size_t)N_DIM * D_DIM;
  const size_t need = (xcnt + wcnt) * sizeof(__bf16);  // ~24 MB

  if (ws_size < need) {
    const long long nblocks = (long long)B_DIM * N_DIM / 256;
    fallback_kernel<<<(int)nblocks, 256, 0, stream>>>(x, W, bias, gumbel, flags, out);
    return;
  }

  __bf16* xh  = (__bf16*)d_ws;
  __bf16* wht = xh + xcnt;

  prep_x<<<xcnt / 4 / 256, 256, 0, stream>>>(x, xh);
  prep_w<<<(N_DIM / 32) * (D_DIM / 32), 256, 0, stream>>>(W, wht);
  gemm_fused<<<(B_DIM / BM) * (N_DIM / BN), THREADS, 0, stream>>>(
      xh, wht, bias, gumbel, flags, out);
}

// Round 12
// 708.091 us; speedup vs baseline: 1.1283x; 1.1283x over previous
//
#include <hip/hip_runtime.h>
#include <hip/hip_bf16.h>

// Problem constants (match reference)
#define B_DIM 8192
#define D_DIM 1024
#define N_DIM 4096
#define TAU_INV 5.0f

typedef __bf16 bf16x8 __attribute__((ext_vector_type(8)));
typedef __bf16 bf16x4 __attribute__((ext_vector_type(4)));
typedef float  f32x4  __attribute__((ext_vector_type(4)));

// ---------------------------------------------------------------------------
__device__ __forceinline__ void gld_lds16(const void* g, void* l) {
  __builtin_amdgcn_global_load_lds((const __attribute__((address_space(1))) void*)g,
                                   (__attribute__((address_space(3))) void*)l,
                                   16, 0, 0);
}
__device__ __forceinline__ float fast_rcp(float x) {
  return __builtin_amdgcn_rcpf(x);
}
#define MFMA(a, b, c) __builtin_amdgcn_mfma_f32_16x16x32_bf16((a), (b), (c), 0, 0, 0)

// ---------------------------------------------------------------------------
// prep_x: x (f32 [B,D]) -> xh (bf16). Single-term bf16 verified round 10
// (absmax 0.015625 = comparison floor vs 0.064 threshold).
__global__ void prep_x(const float* __restrict__ x, __bf16* __restrict__ xh) {
  const int i = blockIdx.x * blockDim.x + threadIdx.x;
  const int base = i * 4;
  const float4 v = *reinterpret_cast<const float4*>(x + base);
  bf16x4 h;
  h[0] = (__bf16)v.x; h[1] = (__bf16)v.y; h[2] = (__bf16)v.z; h[3] = (__bf16)v.w;
  *reinterpret_cast<bf16x4*>(xh + base) = h;
}

// ---------------------------------------------------------------------------
// prep_w: W (f32 [D,N]) -> wht (bf16 [N,D]) transposed
__global__ void prep_w(const float* __restrict__ W, __bf16* __restrict__ wht) {
  __shared__ float tile[32][33];
  const int tn = blockIdx.x & 127;
  const int tk = blockIdx.x >> 7;
  const int tx = threadIdx.x & 31;
  const int ty = threadIdx.x >> 5;
#pragma unroll
  for (int r = 0; r < 4; ++r) {
    const int k = tk * 32 + ty + r * 8;
    tile[ty + r * 8][tx] = W[(size_t)k * N_DIM + tn * 32 + tx];
  }
  __syncthreads();
#pragma unroll
  for (int r = 0; r < 4; ++r) {
    const int nn = tn * 32 + ty + r * 8;
    const int kk = tk * 32 + tx;
    wht[(size_t)nn * D_DIM + kk] = (__bf16)tile[tx][ty + r * 8];
  }
}

// ---------------------------------------------------------------------------
// Fused GEMM, single-round mega-tile: 512x256 block tile, BK=32, K=1024,
// grid = 256 blocks = 1 block/CU (NO inter-round serialization). 8 waves
// (4M x 2N), wave tile 128x128 -> acc[8][8] f32x4 = 256 AGPR; LDS reads
// halve to 256 B/MFMA vs round-10's 512 (wave-tile perimeter scaling).
// Per K-step per wave: 16 ds_read_b128 + 64 MFMA (deep run hides staging).
// LDS 96 KB (2 dbuf x (32K A + 16K B)); __launch_bounds__(512,1) -> full
// 512-reg budget, no spill (~340 needed). Rotation swizzle (measured 0
// conflicts), counted vmcnt(6), setprio, LDS-transposed epilogue.
#define BM 512
#define BN 256
#define BK 32
#define THREADS 512

__global__ __launch_bounds__(THREADS, 1) void gemm_fused(
    const __bf16* __restrict__ xh,
    const __bf16* __restrict__ wht,
    const float* __restrict__ bias, const float* __restrict__ gumbel,
    const int* __restrict__ flags, float* __restrict__ out) {
  __shared__ __align__(16) __bf16 As[2][BM * BK];  // 2 x 32 KB
  __shared__ __align__(16) __bf16 Bs[2][BN * BK];  // 2 x 16 KB
  float* Ebuf = reinterpret_cast<float*>(&As[0][0]);  // 32 KB epilogue buffer

  const int tid  = threadIdx.x;
  const int lane = tid & 63;
  const int wave = tid >> 6;       // 0..7
  const int wr   = wave >> 1;      // 0..3 (M, 128 rows each)
  const int wc   = wave & 1;       // 0..1 (N, 128 cols each)
  const int fr   = lane & 15;
  const int q4   = lane >> 4;
  // rotation swizzle (round-5/10, measured conflict-free)
  const int prot8 = ((q4 + ((fr >> 1) & 3)) & 3) * 8;

  // XCD swizzle: 256 blocks; each XCD owns 2 row-panels (A 2 MB L2-resident)
  // x all 16 col-panels; B (8 MB total) served by L3.
  const int bx  = blockIdx.x;
  const int xcd = bx & 7;
  const int ii  = bx >> 3;             // 0..31
  const int tm  = xcd * 2 + (ii & 1);  // 0..15
  const int tn  = ii >> 1;             // 0..15
  const int row0 = tm * BM;
  const int col0 = tn * BN;

  // staging geometry: chunk c = i*512+tid -> row = i*128 + (tid>>2),
  // phys slot tid&3; logical slot l = (p - (row>>1)) & 3 — constant in i
  // since i*128 rows shift (row>>1) by multiples of 64 (=0 mod 4).
  const int r0 = tid >> 2;                               // 0..127
  const int l8 = (((tid & 3) - ((tid >> 3) & 3)) & 3) * 8;

  const __bf16* Ahi = xh  + (size_t)row0 * D_DIM;
  const __bf16* Bsc = wht + (size_t)col0 * D_DIM;

#define STAGE(b, t_)                                                         \
  do {                                                                       \
    const int ko_ = (t_) * 32;                                               \
    _Pragma("unroll")                                                        \
    for (int i_ = 0; i_ < 4; ++i_)                                           \
      gld_lds16(Ahi + (size_t)(i_ * 128 + r0) * D_DIM + ko_ + l8,            \
                &As[b][(i_ * 512 + tid) * 8]);                               \
    _Pragma("unroll")                                                        \
    for (int i_ = 0; i_ < 2; ++i_)                                           \
      gld_lds16(Bsc + (size_t)(i_ * 128 + r0) * D_DIM + ko_ + l8,            \
                &Bs[b][(i_ * 512 + tid) * 8]);                               \
  } while (0)

#define COMPUTE(b)                                                           \
  {                                                                          \
    bf16x8 af_[8], bf_[8];                                                   \
    _Pragma("unroll")                                                        \
    for (int m = 0; m < 8; ++m)                                              \
      af_[m] = *reinterpret_cast<const bf16x8*>(                             \
          &As[b][(wr * 128 + m * 16 + fr) * BK + prot8]);                    \
    _Pragma("unroll")                                                        \
    for (int n = 0; n < 8; ++n)                                              \
      bf_[n] = *reinterpret_cast<const bf16x8*>(                             \
          &Bs[b][(wc * 128 + n * 16 + fr) * BK + prot8]);                    \
    __builtin_amdgcn_s_setprio(1);                                           \
    _Pragma("unroll")                                                        \
    for (int m = 0; m < 8; ++m)                                              \
      _Pragma("unroll")                                                      \
      for (int n = 0; n < 8; ++n)                                            \
        acc[m][n] = MFMA(bf_[n], af_[m], acc[m][n]);                         \
    __builtin_amdgcn_s_setprio(0);                                           \
  }

#define VM6 asm volatile("s_waitcnt vmcnt(6)" ::: "memory")
#define VM0 asm volatile("s_waitcnt vmcnt(0)" ::: "memory")
#define BAR __builtin_amdgcn_s_barrier()

  f32x4 acc[8][8];
#pragma unroll
  for (int m = 0; m < 8; ++m)
#pragma unroll
    for (int n = 0; n < 8; ++n) acc[m][n] = (f32x4){0.f, 0.f, 0.f, 0.f};

  STAGE(0, 0);
#pragma unroll 1
  for (int it = 0; it < 15; ++it) {
    STAGE(1, 2 * it + 1);
    VM6; BAR;
    COMPUTE(0)
    BAR;
    STAGE(0, 2 * it + 2);
    VM6; BAR;
    COMPUTE(1)
    BAR;
  }
  STAGE(1, 31);
  VM6; BAR;
  COMPUTE(0)
  BAR;
  VM0; BAR;
  COMPUTE(1)

  // ---- LDS-transposed epilogue ----
  // 16 chunks of 32 rows (512 total). Owner waves (wr == ck>>2, both wc)
  // write acc frags into Ebuf[32][256] floats (16B-slot XOR swizzle), then
  // all 8 waves stream back row-contiguous (wave w, round rr -> row rr*8+w,
  // lanes cover 256 cols) -> 1 KB contiguous wave-segments for out0/out1
  // stores and gumbel loads. ck fully unrolled: acc indices static (rule #20).
  float* out0 = out;
  float* out1 = out + (size_t)B_DIM * N_DIM;

  const int tcol = tid & 63;            // 16B col-chunk within 256-col tile
  const int gcol = col0 + tcol * 4;
  const float4 bias4 = *reinterpret_cast<const float4*>(bias + gcol);
  const int flag = flags[(col0 >> 4) + (tcol >> 2)];

#pragma unroll
  for (int ck = 0; ck < 16; ++ck) {
    __syncthreads();   // prior chunk reads / K-loop LDS use complete
    if (wr == (ck >> 2)) {
#pragma unroll
      for (int mi = 0; mi < 2; ++mi) {
        const int lrow = mi * 16 + fr;          // 0..31
        const int m = (ck & 3) * 2 + mi;        // static per unrolled ck
#pragma unroll
        for (int n = 0; n < 8; ++n) {
          const int s = (wc * 32 + n * 4 + q4) ^ (lrow & 7);  // 16B slot 0..63
          *reinterpret_cast<f32x4*>(&Ebuf[lrow * 256 + s * 4]) = acc[m][n];
        }
      }
    }
    __syncthreads();
#pragma unroll
    for (int rr = 0; rr < 4; ++rr) {
      const int lrow = rr * 8 + wave;           // 0..31
      const int grow = row0 + ck * 32 + lrow;
      const f32x4 a = *reinterpret_cast<const f32x4*>(
          &Ebuf[lrow * 256 + (tcol ^ (lrow & 7)) * 4]);
      const size_t idx = (size_t)grow * N_DIM + gcol;
      const float o0 = a[0] + bias4.x;
      const float o1 = a[1] + bias4.y;
      const float o2 = a[2] + bias4.z;
      const float o3 = a[3] + bias4.w;
      *reinterpret_cast<float4*>(out0 + idx) = make_float4(o0, o1, o2, o3);

      float4 v;
      if (flag == 0) {
        const float c0 = fminf(fmaxf(o0, -15.f), 15.f);
        const float c1 = fminf(fmaxf(o1, -15.f), 15.f);
        const float c2 = fminf(fmaxf(o2, -15.f), 15.f);
        const float c3 = fminf(fmaxf(o3, -15.f), 15.f);
        const float e0 = __expf(2.f * c0), e1 = __expf(2.f * c1);
        const float e2 = __expf(2.f * c2), e3 = __expf(2.f * c3);
        v.x = (e0 - 1.f) * fast_rcp(e0 + 1.f);
        v.y = (e1 - 1.f) * fast_rcp(e1 + 1.f);
        v.z = (e2 - 1.f) * fast_rcp(e2 + 1.f);
        v.w = (e3 - 1.f) * fast_rcp(e3 + 1.f);
      } else {
        // 16-wide segment = 4 adjacent lanes: shfl_xor 1,2
        const float4 g = *reinterpret_cast<const float4*>(gumbel + idx);
        const float t0 = (o0 + g.x) * TAU_INV;
        const float t1 = (o1 + g.y) * TAU_INV;
        const float t2 = (o2 + g.z) * TAU_INV;
        const float t3 = (o3 + g.w) * TAU_INV;
        float mx = fmaxf(fmaxf(t0, t1), fmaxf(t2, t3));
        mx = fmaxf(mx, __shfl_xor(mx, 1));
        mx = fmaxf(mx, __shfl_xor(mx, 2));
        const float e0 = __expf(t0 - mx), e1 = __expf(t1 - mx);
        const float e2 = __expf(t2 - mx), e3 = __expf(t3 - mx);
        float s = (e0 + e1) + (e2 + e3);
        s += __shfl_xor(s, 1);
        s += __shfl_xor(s, 2);
        const float inv = fast_rcp(s);
        v.x = e0 * inv; v.y = e1 * inv; v.z = e2 * inv; v.w = e3 * inv;
      }
      *reinterpret_cast<float4*>(out1 + idx) = v;
    }
  }
}

// ---------------------------------------------------------------------------
// fallback (only if ws_size too small): naive but correct
__global__ void fallback_kernel(const float* __restrict__ x, const float* __restrict__ W,
                                const float* __restrict__ bias, const float* __restrict__ gumbel,
                                const int* __restrict__ flags, float* __restrict__ out) {
  const size_t idx = (size_t)blockIdx.x * blockDim.x + threadIdx.x;
  const int row = (int)(idx / N_DIM);
  const int col = (int)(idx % N_DIM);
  float o = bias[col];
  const float* xr = x + (size_t)row * D_DIM;
  for (int k = 0; k < D_DIM; ++k) o += xr[k] * W[(size_t)k * N_DIM + col];
  out[idx] = o;
  float v;
  if (flags[col >> 4] == 0) {
    const float oc = fminf(fmaxf(o, -15.f), 15.f);
    const float e2 = __expf(2.f * oc);
    v = (e2 - 1.f) / (e2 + 1.f);
  } else {
    const float t = (o + gumbel[idx]) * TAU_INV;
    float mx = t;
    mx = fmaxf(mx, __shfl_xor(mx, 1));
    mx = fmaxf(mx, __shfl_xor(mx, 2));
    mx = fmaxf(mx, __shfl_xor(mx, 4));
    mx = fmaxf(mx, __shfl_xor(mx, 8));
    float e = __expf(t - mx);
    float ssum = e;
    ssum += __shfl_xor(ssum, 1);
    ssum += __shfl_xor(ssum, 2);
    ssum += __shfl_xor(ssum, 4);
    ssum += __shfl_xor(ssum, 8);
    v = e / ssum;
  }
  out[(size_t)B_DIM * N_DIM + idx] = v;
}

// ---------------------------------------------------------------------------
extern "C" void kernel_launch(void* const* d_in, const int* in_sizes, int n_in,
                              void* d_out, int out_size, void* d_ws, size_t ws_size,
                              hipStream_t stream) {
  const float* x      = (const float*)d_in[0];
  const float* W      = (const float*)d_in[1];
  const float* bias   = (const float*)d_in[2];
  const float* gumbel = (const float*)d_in[3];
  const int*   flags  = (const int*)d_in[4];
  float* out = (float*)d_out;

  const size_t xcnt = (size_t)B_DIM * D_DIM;
  const size_t wcnt = (size_t)N_DIM * D_DIM;
  const size_t need = (xcnt + wcnt) * sizeof(__bf16);  // ~24 MB

  if (ws_size < need) {
    const long long nblocks = (long long)B_DIM * N_DIM / 256;
    fallback_kernel<<<(int)nblocks, 256, 0, stream>>>(x, W, bias, gumbel, flags, out);
    return;
  }

  __bf16* xh  = (__bf16*)d_ws;
  __bf16* wht = xh + xcnt;

  prep_x<<<xcnt / 4 / 256, 256, 0, stream>>>(x, xh);
  prep_w<<<(N_DIM / 32) * (D_DIM / 32), 256, 0, stream>>>(W, wht);
  gemm_fused<<<(B_DIM / BM) * (N_DIM / BN), THREADS, 0, stream>>>(
      xh, wht, bias, gumbel, flags, out);
}

// Round 14
// 155.885 us; speedup vs baseline: 5.1252x; 4.5424x over previous
//
#include <hip/hip_runtime.h>
#include <hip/hip_bf16.h>

// Problem constants (match reference)
#define B_DIM 8192
#define D_DIM 1024
#define N_DIM 4096
#define TAU_INV 5.0f

typedef __bf16 bf16x8 __attribute__((ext_vector_type(8)));
typedef __bf16 bf16x4 __attribute__((ext_vector_type(4)));
typedef float  f32x4  __attribute__((ext_vector_type(4)));

// ---------------------------------------------------------------------------
__device__ __forceinline__ void gld_lds16(const void* g, void* l) {
  __builtin_amdgcn_global_load_lds((const __attribute__((address_space(1))) void*)g,
                                   (__attribute__((address_space(3))) void*)l,
                                   16, 0, 0);
}
__device__ __forceinline__ float fast_rcp(float x) {
  return __builtin_amdgcn_rcpf(x);
}
#define MFMA(a, b, c) __builtin_amdgcn_mfma_f32_16x16x32_bf16((a), (b), (c), 0, 0, 0)

// ---------------------------------------------------------------------------
// prep_x: x (f32 [B,D]) -> xh (bf16). Single-term bf16 verified round 10
// (absmax 0.015625 = comparison floor vs 0.064 threshold).
__global__ void prep_x(const float* __restrict__ x, __bf16* __restrict__ xh) {
  const int i = blockIdx.x * blockDim.x + threadIdx.x;
  const int base = i * 4;
  const float4 v = *reinterpret_cast<const float4*>(x + base);
  bf16x4 h;
  h[0] = (__bf16)v.x; h[1] = (__bf16)v.y; h[2] = (__bf16)v.z; h[3] = (__bf16)v.w;
  *reinterpret_cast<bf16x4*>(xh + base) = h;
}

// ---------------------------------------------------------------------------
// prep_w: W (f32 [D,N]) -> wht (bf16 [N,D]) transposed
__global__ void prep_w(const float* __restrict__ W, __bf16* __restrict__ wht) {
  __shared__ float tile[32][33];
  const int tn = blockIdx.x & 127;
  const int tk = blockIdx.x >> 7;
  const int tx = threadIdx.x & 31;
  const int ty = threadIdx.x >> 5;
#pragma unroll
  for (int r = 0; r < 4; ++r) {
    const int k = tk * 32 + ty + r * 8;
    tile[ty + r * 8][tx] = W[(size_t)k * N_DIM + tn * 32 + tx];
  }
  __syncthreads();
#pragma unroll
  for (int r = 0; r < 4; ++r) {
    const int nn = tn * 32 + ty + r * 8;
    const int kk = tk * 32 + tx;
    wht[(size_t)nn * D_DIM + kk] = (__bf16)tile[tx][ty + r * 8];
  }
}

// ---------------------------------------------------------------------------
// Fused GEMM: 128x256 tile, BK=32, K=1024 single-term bf16, 8 waves (2Mx4N),
// wave tile 64x64 (acc 64 VGPR — round-8-proven no-spill config). Double-
// buffered LDS 48 KB + counted vmcnt(3) (stage t+1 issued before compute t,
// never drain to 0 in-loop) -> L2 stage latency hides under prior compute.
// 2 blocks/CU. Rotation swizzle (measured 0 conflicts), setprio, LDS-
// transposed epilogue with NON-TEMPORAL out/gumbel (write-once data bypasses
// L2 allocation; bias/flags stay cached). nt ops use ext_vector f32x4
// (HIP_vector_type float4 is a struct — rejected by the builtin, round 13).
#define BM 128
#define BN 256
#define BK 32
#define THREADS 512

__global__ __launch_bounds__(THREADS, 4) void gemm_fused(
    const __bf16* __restrict__ xh,
    const __bf16* __restrict__ wht,
    const float* __restrict__ bias, const float* __restrict__ gumbel,
    const int* __restrict__ flags, float* __restrict__ out) {
  __shared__ __align__(16) __bf16 As[2][BM * BK];  // 2 x 8 KB
  __shared__ __align__(16) __bf16 Bs[2][BN * BK];  // 2 x 16 KB
  float* Ebuf = reinterpret_cast<float*>(&Bs[0][0]);  // 32 KB epilogue buffer

  const int tid  = threadIdx.x;
  const int lane = tid & 63;
  const int wave = tid >> 6;
  const int wr   = wave >> 2;      // 0..1 (M, 64 rows each)
  const int wc   = wave & 3;       // 0..3 (N, 64 cols each)
  const int fr   = lane & 15;
  const int q4   = lane >> 4;
  // rotation swizzle (round-5/8/10, measured conflict-free)
  const int prot8 = ((q4 + ((fr >> 1) & 3)) & 3) * 8;

  // XCD swizzle: 1024 blocks; each XCD owns 8 row-panels x 16 col-panels
  const int bx  = blockIdx.x;
  const int xcd = bx & 7;
  const int ii  = bx >> 3;         // 0..127
  const int tn  = ii >> 3;         // 0..15
  const int tm  = xcd * 8 + (ii & 7);  // 0..63
  const int row0 = tm * BM;
  const int col0 = tn * BN;

  // staging geometry: chunk c -> row c>>2, phys slot c&3,
  // logical (global) slot l = (p - (row>>1)) & 3 (inverse of read rotation)
  const int r0 = tid >> 2;                               // 0..127
  const int l8 = (((tid & 3) - ((tid >> 3) & 3)) & 3) * 8;

  const __bf16* Ahi = xh  + (size_t)row0 * D_DIM;
  const __bf16* Bsc = wht + (size_t)col0 * D_DIM;

#define STAGE(b, t_)                                                         \
  do {                                                                       \
    const int ko_ = (t_) * 32;                                               \
    gld_lds16(Ahi + (size_t)r0 * D_DIM + ko_ + l8, &As[b][tid * 8]);         \
    gld_lds16(Bsc + (size_t)r0 * D_DIM + ko_ + l8, &Bs[b][tid * 8]);         \
    gld_lds16(Bsc + (size_t)(128 + r0) * D_DIM + ko_ + l8,                   \
              &Bs[b][(512 + tid) * 8]);                                      \
  } while (0)

#define COMPUTE(b)                                                           \
  {                                                                          \
    bf16x8 bfr_[4];                                                          \
    _Pragma("unroll")                                                        \
    for (int n = 0; n < 4; ++n)                                              \
      bfr_[n] = *reinterpret_cast<const bf16x8*>(                            \
          &Bs[b][(wc * 64 + n * 16 + fr) * BK + prot8]);                     \
    __builtin_amdgcn_s_setprio(1);                                           \
    _Pragma("unroll")                                                        \
    for (int m = 0; m < 4; ++m) {                                            \
      const bf16x8 av_ = *reinterpret_cast<const bf16x8*>(                   \
          &As[b][(wr * 64 + m * 16 + fr) * BK + prot8]);                     \
      _Pragma("unroll")                                                      \
      for (int n = 0; n < 4; ++n)                                            \
        acc[m][n] = MFMA(bfr_[n], av_, acc[m][n]);                           \
    }                                                                        \
    __builtin_amdgcn_s_setprio(0);                                           \
  }

#define VM3 asm volatile("s_waitcnt vmcnt(3)" ::: "memory")
#define VM0 asm volatile("s_waitcnt vmcnt(0)" ::: "memory")
#define BAR __builtin_amdgcn_s_barrier()

  f32x4 acc[4][4];
#pragma unroll
  for (int m = 0; m < 4; ++m)
#pragma unroll
    for (int n = 0; n < 4; ++n) acc[m][n] = (f32x4){0.f, 0.f, 0.f, 0.f};

  STAGE(0, 0);
#pragma unroll 1
  for (int it = 0; it < 15; ++it) {
    STAGE(1, 2 * it + 1);
    VM3; BAR;
    COMPUTE(0)
    BAR;
    STAGE(0, 2 * it + 2);
    VM3; BAR;
    COMPUTE(1)
    BAR;
  }
  STAGE(1, 31);
  VM3; BAR;
  COMPUTE(0)
  BAR;
  VM0; BAR;
  COMPUTE(1)

  // ---- LDS-transposed epilogue (non-temporal global traffic) ----
  // 4 chunks of 32 rows. Owner waves (wr == ck>>1) write acc frags into
  // Ebuf[32][256] floats (16B-slot XOR swizzle), then all 8 waves stream
  // back row-contiguous (wave w, round rr -> row rr*8+w, lanes cover 256
  // cols) -> 1 KB contiguous wave-segments; out0/out1 stores and gumbel
  // loads use nt (bypass L2 allocation — write-once/read-once data).
  float* out0 = out;
  float* out1 = out + (size_t)B_DIM * N_DIM;

  const int tcol = tid & 63;            // 16B col-chunk within 256-col tile
  const int gcol = col0 + tcol * 4;
  const float4 bias4 = *reinterpret_cast<const float4*>(bias + gcol);
  const int flag = flags[(col0 >> 4) + (tcol >> 2)];

#pragma unroll
  for (int ck = 0; ck < 4; ++ck) {
    __syncthreads();   // prior chunk reads / K-loop LDS use complete
    if (wr == (ck >> 1)) {
#pragma unroll
      for (int mi = 0; mi < 2; ++mi) {
        const int lrow = mi * 16 + fr;          // 0..31
        const int m = (ck & 1) * 2 + mi;
#pragma unroll
        for (int n = 0; n < 4; ++n) {
          const int s = (wc * 16 + n * 4 + q4) ^ (lrow & 7);  // 16B slot 0..63
          *reinterpret_cast<f32x4*>(&Ebuf[lrow * 256 + s * 4]) = acc[m][n];
        }
      }
    }
    __syncthreads();
#pragma unroll
    for (int rr = 0; rr < 4; ++rr) {
      const int lrow = rr * 8 + wave;           // 0..31
      const int grow = row0 + ck * 32 + lrow;
      const f32x4 a = *reinterpret_cast<const f32x4*>(
          &Ebuf[lrow * 256 + (tcol ^ (lrow & 7)) * 4]);
      const size_t idx = (size_t)grow * N_DIM + gcol;
      const float o0 = a[0] + bias4.x;
      const float o1 = a[1] + bias4.y;
      const float o2 = a[2] + bias4.z;
      const float o3 = a[3] + bias4.w;
      f32x4 ov = {o0, o1, o2, o3};
      __builtin_nontemporal_store(ov, reinterpret_cast<f32x4*>(out0 + idx));

      f32x4 v;
      if (flag == 0) {
        const float c0 = fminf(fmaxf(o0, -15.f), 15.f);
        const float c1 = fminf(fmaxf(o1, -15.f), 15.f);
        const float c2 = fminf(fmaxf(o2, -15.f), 15.f);
        const float c3 = fminf(fmaxf(o3, -15.f), 15.f);
        const float e0 = __expf(2.f * c0), e1 = __expf(2.f * c1);
        const float e2 = __expf(2.f * c2), e3 = __expf(2.f * c3);
        v[0] = (e0 - 1.f) * fast_rcp(e0 + 1.f);
        v[1] = (e1 - 1.f) * fast_rcp(e1 + 1.f);
        v[2] = (e2 - 1.f) * fast_rcp(e2 + 1.f);
        v[3] = (e3 - 1.f) * fast_rcp(e3 + 1.f);
      } else {
        // 16-wide segment = 4 adjacent lanes: shfl_xor 1,2
        const f32x4 g = __builtin_nontemporal_load(
            reinterpret_cast<const f32x4*>(gumbel + idx));
        const float t0 = (o0 + g[0]) * TAU_INV;
        const float t1 = (o1 + g[1]) * TAU_INV;
        const float t2 = (o2 + g[2]) * TAU_INV;
        const float t3 = (o3 + g[3]) * TAU_INV;
        float mx = fmaxf(fmaxf(t0, t1), fmaxf(t2, t3));
        mx = fmaxf(mx, __shfl_xor(mx, 1));
        mx = fmaxf(mx, __shfl_xor(mx, 2));
        const float e0 = __expf(t0 - mx), e1 = __expf(t1 - mx);
        const float e2 = __expf(t2 - mx), e3 = __expf(t3 - mx);
        float s = (e0 + e1) + (e2 + e3);
        s += __shfl_xor(s, 1);
        s += __shfl_xor(s, 2);
        const float inv = fast_rcp(s);
        v[0] = e0 * inv; v[1] = e1 * inv; v[2] = e2 * inv; v[3] = e3 * inv;
      }
      __builtin_nontemporal_store(v, reinterpret_cast<f32x4*>(out1 + idx));
    }
  }
}

// ---------------------------------------------------------------------------
// fallback (only if ws_size too small): naive but correct
__global__ void fallback_kernel(const float* __restrict__ x, const float* __restrict__ W,
                                const float* __restrict__ bias, const float* __restrict__ gumbel,
                                const int* __restrict__ flags, float* __restrict__ out) {
  const size_t idx = (size_t)blockIdx.x * blockDim.x + threadIdx.x;
  const int row = (int)(idx / N_DIM);
  const int col = (int)(idx % N_DIM);
  float o = bias[col];
  const float* xr = x + (size_t)row * D_DIM;
  for (int k = 0; k < D_DIM; ++k) o += xr[k] * W[(size_t)k * N_DIM + col];
  out[idx] = o;
  float v;
  if (flags[col >> 4] == 0) {
    const float oc = fminf(fmaxf(o, -15.f), 15.f);
    const float e2 = __expf(2.f * oc);
    v = (e2 - 1.f) / (e2 + 1.f);
  } else {
    const float t = (o + gumbel[idx]) * TAU_INV;
    float mx = t;
    mx = fmaxf(mx, __shfl_xor(mx, 1));
    mx = fmaxf(mx, __shfl_xor(mx, 2));
    mx = fmaxf(mx, __shfl_xor(mx, 4));
    mx = fmaxf(mx, __shfl_xor(mx, 8));
    float e = __expf(t - mx);
    float ssum = e;
    ssum += __shfl_xor(ssum, 1);
    ssum += __shfl_xor(ssum, 2);
    ssum += __shfl_xor(ssum, 4);
    ssum += __shfl_xor(ssum, 8);
    v = e / ssum;
  }
  out[(size_t)B_DIM * N_DIM + idx] = v;
}

// ---------------------------------------------------------------------------
extern "C" void kernel_launch(void* const* d_in, const int* in_sizes, int n_in,
                              void* d_out, int out_size, void* d_ws, size_t ws_size,
                              hipStream_t stream) {
  const float* x      = (const float*)d_in[0];
  const float* W      = (const float*)d_in[1];
  const float* bias   = (const float*)d_in[2];
  const float* gumbel = (const float*)d_in[3];
  const int*   flags  = (const int*)d_in[4];
  float* out = (float*)d_out;

  const size_t xcnt = (size_t)B_DIM * D_DIM;
  const size_t wcnt = (size_t)N_DIM * D_DIM;
  const size_t need = (xcnt + wcnt) * sizeof(__bf16);  // ~24 MB

  if (ws_size < need) {
    const long long nblocks = (long long)B_DIM * N_DIM / 256;
    fallback_kernel<<<(int)nblocks, 256, 0, stream>>>(x, W, bias, gumbel, flags, out);
    return;
  }

  __bf16* xh  = (__bf16*)d_ws;
  __bf16* wht = xh + xcnt;

  prep_x<<<xcnt / 4 / 256, 256, 0, stream>>>(x, xh);
  prep_w<<<(N_DIM / 32) * (D_DIM / 32), 256, 0, stream>>>(W, wht);
  gemm_fused<<<(B_DIM / BM) * (N_DIM / BN), THREADS, 0, stream>>>(
      xh, wht, bias, gumbel, flags, out);
}

// Round 15
// 154.813 us; speedup vs baseline: 5.1607x; 1.0069x over previous
//
#include <hip/hip_runtime.h>
#include <hip/hip_bf16.h>

// Problem constants (match reference)
#define B_DIM 8192
#define D_DIM 1024
#define N_DIM 4096
#define TAU_INV 5.0f

typedef __bf16 bf16x8 __attribute__((ext_vector_type(8)));
typedef __bf16 bf16x4 __attribute__((ext_vector_type(4)));
typedef float  f32x4  __attribute__((ext_vector_type(4)));

// ---------------------------------------------------------------------------
__device__ __forceinline__ void gld_lds16(const void* g, void* l) {
  __builtin_amdgcn_global_load_lds((const __attribute__((address_space(1))) void*)g,
                                   (__attribute__((address_space(3))) void*)l,
                                   16, 0, 0);
}
__device__ __forceinline__ float fast_rcp(float x) {
  return __builtin_amdgcn_rcpf(x);
}
#define MFMA(a, b, c) __builtin_amdgcn_mfma_f32_16x16x32_bf16((a), (b), (c), 0, 0, 0)

// ---------------------------------------------------------------------------
// prep_w: W (f32 [D,N]) -> wht (bf16 [N,D]) transposed
__global__ void prep_w(const float* __restrict__ W, __bf16* __restrict__ wht) {
  __shared__ float tile[32][33];
  const int tn = blockIdx.x & 127;
  const int tk = blockIdx.x >> 7;
  const int tx = threadIdx.x & 31;
  const int ty = threadIdx.x >> 5;
#pragma unroll
  for (int r = 0; r < 4; ++r) {
    const int k = tk * 32 + ty + r * 8;
    tile[ty + r * 8][tx] = W[(size_t)k * N_DIM + tn * 32 + tx];
  }
  __syncthreads();
#pragma unroll
  for (int r = 0; r < 4; ++r) {
    const int nn = tn * 32 + ty + r * 8;
    const int kk = tk * 32 + tx;
    wht[(size_t)nn * D_DIM + kk] = (__bf16)tile[tx][ty + r * 8];
  }
}

// ---------------------------------------------------------------------------
// Fused GEMM: 128x256 tile, BK=32, K=1024 single-term bf16 (absmax floor
// verified round 10), 8 waves (2Mx4N), wave tile 64x64 (acc 64 VGPR).
// This round: (1) single-__syncthreads-per-K-step double-buffer (T3 minimum
// recipe: issue STAGE(t+1) -> COMPUTE(t) -> A-write-late -> barrier; the one
// barrier both publishes buf t+1 and retires reads of buf t); (2) prep_x
// FUSED: A staged via global f32 loads + (__bf16) cvt + ds_write_b128 (T14
// issue-early/write-late split; source pre-rotated, dest linear, read
// rotated — same mapping as the gld_lds path). B stays gld_lds. nt epilogue.
#define BM 128
#define BN 256
#define BK 32
#define THREADS 512

__global__ __launch_bounds__(THREADS, 4) void gemm_fused(
    const float* __restrict__ x,
    const __bf16* __restrict__ wht,
    const float* __restrict__ bias, const float* __restrict__ gumbel,
    const int* __restrict__ flags, float* __restrict__ out) {
  __shared__ __align__(16) __bf16 As[2][BM * BK];  // 2 x 8 KB
  __shared__ __align__(16) __bf16 Bs[2][BN * BK];  // 2 x 16 KB
  float* Ebuf = reinterpret_cast<float*>(&Bs[0][0]);  // 32 KB epilogue buffer

  const int tid  = threadIdx.x;
  const int lane = tid & 63;
  const int wave = tid >> 6;
  const int wr   = wave >> 2;      // 0..1 (M, 64 rows each)
  const int wc   = wave & 3;       // 0..3 (N, 64 cols each)
  const int fr   = lane & 15;
  const int q4   = lane >> 4;
  // rotation swizzle (round-5/8/10, measured conflict-free)
  const int prot8 = ((q4 + ((fr >> 1) & 3)) & 3) * 8;

  // XCD swizzle: 1024 blocks; each XCD owns 8 row-panels x 16 col-panels
  const int bx  = blockIdx.x;
  const int xcd = bx & 7;
  const int ii  = bx >> 3;         // 0..127
  const int tn  = ii >> 3;         // 0..15
  const int tm  = xcd * 8 + (ii & 7);  // 0..63
  const int row0 = tm * BM;
  const int col0 = tn * BN;

  // staging geometry: chunk c -> row c>>2, phys slot c&3,
  // logical (global) slot l = (p - (row>>1)) & 3 (inverse of read rotation)
  const int r0 = tid >> 2;                               // 0..127
  const int l8 = (((tid & 3) - ((tid >> 3) & 3)) & 3) * 8;

  const float*  Axf = x   + (size_t)row0 * D_DIM;
  const __bf16* Bsc = wht + (size_t)col0 * D_DIM;

  f32x4 a0_, a1_;   // in-flight A registers (f32, pre-cvt)

#define ALOAD(t_)                                                            \
  do {                                                                       \
    const size_t o_ = (size_t)r0 * D_DIM + (t_) * 32 + l8;                   \
    a0_ = *reinterpret_cast<const f32x4*>(Axf + o_);                         \
    a1_ = *reinterpret_cast<const f32x4*>(Axf + o_ + 4);                     \
  } while (0)

#define CVTW(b)                                                              \
  do {                                                                       \
    bf16x8 h_;                                                               \
    h_[0] = (__bf16)a0_[0]; h_[1] = (__bf16)a0_[1];                          \
    h_[2] = (__bf16)a0_[2]; h_[3] = (__bf16)a0_[3];                          \
    h_[4] = (__bf16)a1_[0]; h_[5] = (__bf16)a1_[1];                          \
    h_[6] = (__bf16)a1_[2]; h_[7] = (__bf16)a1_[3];                          \
    *reinterpret_cast<bf16x8*>(&As[b][tid * 8]) = h_;                        \
  } while (0)

#define BGLD(b, t_)                                                          \
  do {                                                                       \
    const int ko_ = (t_) * 32;                                               \
    gld_lds16(Bsc + (size_t)r0 * D_DIM + ko_ + l8, &Bs[b][tid * 8]);         \
    gld_lds16(Bsc + (size_t)(128 + r0) * D_DIM + ko_ + l8,                   \
              &Bs[b][(512 + tid) * 8]);                                      \
  } while (0)

#define COMPUTE(b)                                                           \
  {                                                                          \
    bf16x8 bfr_[4];                                                          \
    _Pragma("unroll")                                                        \
    for (int n = 0; n < 4; ++n)                                              \
      bfr_[n] = *reinterpret_cast<const bf16x8*>(                            \
          &Bs[b][(wc * 64 + n * 16 + fr) * BK + prot8]);                     \
    __builtin_amdgcn_s_setprio(1);                                           \
    _Pragma("unroll")                                                        \
    for (int m = 0; m < 4; ++m) {                                            \
      const bf16x8 av_ = *reinterpret_cast<const bf16x8*>(                   \
          &As[b][(wr * 64 + m * 16 + fr) * BK + prot8]);                     \
      _Pragma("unroll")                                                      \
      for (int n = 0; n < 4; ++n)                                            \
        acc[m][n] = MFMA(bfr_[n], av_, acc[m][n]);                           \
    }                                                                        \
    __builtin_amdgcn_s_setprio(0);                                           \
  }

  f32x4 acc[4][4];
#pragma unroll
  for (int m = 0; m < 4; ++m)
#pragma unroll
    for (int n = 0; n < 4; ++n) acc[m][n] = (f32x4){0.f, 0.f, 0.f, 0.f};

  // prologue: stage K-tile 0 into buf 0
  ALOAD(0);
  BGLD(0, 0);
  CVTW(0);
  __syncthreads();   // drains vmcnt (B gld) + lgkmcnt (A ds_write)

  // single-barrier dbuf loop: issue stage(t+1) -> compute(t) -> A-write ->
  // one __syncthreads (publishes buf t+1, retires reads of buf t).
#pragma unroll 1
  for (int it = 0; it < 15; ++it) {
    ALOAD(2 * it + 1); BGLD(1, 2 * it + 1);
    COMPUTE(0)
    CVTW(1);
    __syncthreads();
    ALOAD(2 * it + 2); BGLD(0, 2 * it + 2);
    COMPUTE(1)
    CVTW(0);
    __syncthreads();
  }
  ALOAD(31); BGLD(1, 31);
  COMPUTE(0)
  CVTW(1);
  __syncthreads();
  COMPUTE(1)

  // ---- LDS-transposed epilogue (non-temporal global traffic) ----
  float* out0 = out;
  float* out1 = out + (size_t)B_DIM * N_DIM;

  const int tcol = tid & 63;            // 16B col-chunk within 256-col tile
  const int gcol = col0 + tcol * 4;
  const float4 bias4 = *reinterpret_cast<const float4*>(bias + gcol);
  const int flag = flags[(col0 >> 4) + (tcol >> 2)];

#pragma unroll
  for (int ck = 0; ck < 4; ++ck) {
    __syncthreads();   // prior chunk reads / K-loop LDS use complete
    if (wr == (ck >> 1)) {
#pragma unroll
      for (int mi = 0; mi < 2; ++mi) {
        const int lrow = mi * 16 + fr;          // 0..31
        const int m = (ck & 1) * 2 + mi;
#pragma unroll
        for (int n = 0; n < 4; ++n) {
          const int s = (wc * 16 + n * 4 + q4) ^ (lrow & 7);  // 16B slot 0..63
          *reinterpret_cast<f32x4*>(&Ebuf[lrow * 256 + s * 4]) = acc[m][n];
        }
      }
    }
    __syncthreads();
#pragma unroll
    for (int rr = 0; rr < 4; ++rr) {
      const int lrow = rr * 8 + wave;           // 0..31
      const int grow = row0 + ck * 32 + lrow;
      const f32x4 a = *reinterpret_cast<const f32x4*>(
          &Ebuf[lrow * 256 + (tcol ^ (lrow & 7)) * 4]);
      const size_t idx = (size_t)grow * N_DIM + gcol;
      const float o0 = a[0] + bias4.x;
      const float o1 = a[1] + bias4.y;
      const float o2 = a[2] + bias4.z;
      const float o3 = a[3] + bias4.w;
      f32x4 ov = {o0, o1, o2, o3};
      __builtin_nontemporal_store(ov, reinterpret_cast<f32x4*>(out0 + idx));

      f32x4 v;
      if (flag == 0) {
        const float c0 = fminf(fmaxf(o0, -15.f), 15.f);
        const float c1 = fminf(fmaxf(o1, -15.f), 15.f);
        const float c2 = fminf(fmaxf(o2, -15.f), 15.f);
        const float c3 = fminf(fmaxf(o3, -15.f), 15.f);
        const float e0 = __expf(2.f * c0), e1 = __expf(2.f * c1);
        const float e2 = __expf(2.f * c2), e3 = __expf(2.f * c3);
        v[0] = (e0 - 1.f) * fast_rcp(e0 + 1.f);
        v[1] = (e1 - 1.f) * fast_rcp(e1 + 1.f);
        v[2] = (e2 - 1.f) * fast_rcp(e2 + 1.f);
        v[3] = (e3 - 1.f) * fast_rcp(e3 + 1.f);
      } else {
        // 16-wide segment = 4 adjacent lanes: shfl_xor 1,2
        const f32x4 g = __builtin_nontemporal_load(
            reinterpret_cast<const f32x4*>(gumbel + idx));
        const float t0 = (o0 + g[0]) * TAU_INV;
        const float t1 = (o1 + g[1]) * TAU_INV;
        const float t2 = (o2 + g[2]) * TAU_INV;
        const float t3 = (o3 + g[3]) * TAU_INV;
        float mx = fmaxf(fmaxf(t0, t1), fmaxf(t2, t3));
        mx = fmaxf(mx, __shfl_xor(mx, 1));
        mx = fmaxf(mx, __shfl_xor(mx, 2));
        const float e0 = __expf(t0 - mx), e1 = __expf(t1 - mx);
        const float e2 = __expf(t2 - mx), e3 = __expf(t3 - mx);
        float s = (e0 + e1) + (e2 + e3);
        s += __shfl_xor(s, 1);
        s += __shfl_xor(s, 2);
        const float inv = fast_rcp(s);
        v[0] = e0 * inv; v[1] = e1 * inv; v[2] = e2 * inv; v[3] = e3 * inv;
      }
      __builtin_nontemporal_store(v, reinterpret_cast<f32x4*>(out1 + idx));
    }
  }
}

// ---------------------------------------------------------------------------
// fallback (only if ws_size too small): naive but correct
__global__ void fallback_kernel(const float* __restrict__ x, const float* __restrict__ W,
                                const float* __restrict__ bias, const float* __restrict__ gumbel,
                                const int* __restrict__ flags, float* __restrict__ out) {
  const size_t idx = (size_t)blockIdx.x * blockDim.x + threadIdx.x;
  const int row = (int)(idx / N_DIM);
  const int col = (int)(idx % N_DIM);
  float o = bias[col];
  const float* xr = x + (size_t)row * D_DIM;
  for (int k = 0; k < D_DIM; ++k) o += xr[k] * W[(size_t)k * N_DIM + col];
  out[idx] = o;
  float v;
  if (flags[col >> 4] == 0) {
    const float oc = fminf(fmaxf(o, -15.f), 15.f);
    const float e2 = __expf(2.f * oc);
    v = (e2 - 1.f) / (e2 + 1.f);
  } else {
    const float t = (o + gumbel[idx]) * TAU_INV;
    float mx = t;
    mx = fmaxf(mx, __shfl_xor(mx, 1));
    mx = fmaxf(mx, __shfl_xor(mx, 2));
    mx = fmaxf(mx, __shfl_xor(mx, 4));
    mx = fmaxf(mx, __shfl_xor(mx, 8));
    float e = __expf(t - mx);
    float ssum = e;
    ssum += __shfl_xor(ssum, 1);
    ssum += __shfl_xor(ssum, 2);
    ssum += __shfl_xor(ssum, 4);
    ssum += __shfl_xor(ssum, 8);
    v = e / ssum;
  }
  out[(size_t)B_DIM * N_DIM + idx] = v;
}

// ---------------------------------------------------------------------------
extern "C" void kernel_launch(void* const* d_in, const int* in_sizes, int n_in,
                              void* d_out, int out_size, void* d_ws, size_t ws_size,
                              hipStream_t stream) {
  const float* x      = (const float*)d_in[0];
  const float* W      = (const float*)d_in[1];
  const float* bias   = (const float*)d_in[2];
  const float* gumbel = (const float*)d_in[3];
  const int*   flags  = (const int*)d_in[4];
  float* out = (float*)d_out;

  const size_t wcnt = (size_t)N_DIM * D_DIM;
  const size_t need = wcnt * sizeof(__bf16);  // ~8 MB

  if (ws_size < need) {
    const long long nblocks = (long long)B_DIM * N_DIM / 256;
    fallback_kernel<<<(int)nblocks, 256, 0, stream>>>(x, W, bias, gumbel, flags, out);
    return;
  }

  __bf16* wht = (__bf16*)d_ws;

  prep_w<<<(N_DIM / 32) * (D_DIM / 32), 256, 0, stream>>>(W, wht);
  gemm_fused<<<(B_DIM / BM) * (N_DIM / BN), THREADS, 0, stream>>>(
      x, wht, bias, gumbel, flags, out);
}